// Round 4
// baseline (266.360 us; speedup 1.0000x reference)
//
#include <hip/hip_runtime.h>
#include <math.h>

#define BB 256
#define LL 500
#define EE 300
#define NROWS (BB * LL)      // 128000
#define NJ 18                // 3 (aw3) + 1 (cw3) + 5 (aw5) + 1 (cw5) + 7 (aw7) + 1 (cw7)
#define TOUT 56              // outputs per block
#define NTILE 9              // ceil(500/56)
#define DROWS 64             // dot rows per block = TOUT + 6 halo (+2 spare)

// ---------------------------------------------------------------------------
// Fully fused: each block handles one (batch, l-tile). 4 waves x (4 groups x
// 16 lanes x 4 rows) = 64 dot-rows kept in LDS; epilogue combines taps +
// sigmoid-gate + tanh in the same block. No workspace, single dispatch.
// ---------------------------------------------------------------------------
__global__ __launch_bounds__(256) void fused_kernel(
    const float* __restrict__ x,
    const float* __restrict__ aw3, const float* __restrict__ ab3,
    const float* __restrict__ cw3, const float* __restrict__ cb3,
    const float* __restrict__ aw5, const float* __restrict__ ab5,
    const float* __restrict__ cw5, const float* __restrict__ cb5,
    const float* __restrict__ aw7, const float* __restrict__ ab7,
    const float* __restrict__ cw7, const float* __restrict__ cb7,
    float* __restrict__ out)
{
    __shared__ float dlds[DROWS][NJ + 1];   // +1 pad -> stride 19, conflict-free

    const int b    = blockIdx.x / NTILE;
    const int t    = blockIdx.x % NTILE;
    const int l0   = t * TOUT - 3;           // global l of local dot-row 0
    const int wave = threadIdx.x >> 6;       // 0..3
    const int lane = threadIdx.x & 63;
    const int g    = lane >> 4;              // 0..3
    const int j    = lane & 15;              // 0..15
    const int lr   = wave * 16 + g * 4;      // local dot-row base (0..60)

    // clamped x row pointers + validity (invalid rows -> zero dots = zero pad)
    bool valid[4];
    const float4* xr[4];
#pragma unroll
    for (int rr = 0; rr < 4; ++rr) {
        const int l = l0 + lr + rr;
        valid[rr] = (l >= 0) && (l < LL);
        const int lc = l < 0 ? 0 : (l >= LL ? LL - 1 : l);
        xr[rr] = (const float4*)(x + ((size_t)b * LL + lc) * EE);
    }

    const float* const wptr[NJ] = {
        aw3, aw3 + 300, aw3 + 600, cw3,
        aw5, aw5 + 300, aw5 + 600, aw5 + 900, aw5 + 1200, cw5,
        aw7, aw7 + 300, aw7 + 600, aw7 + 900, aw7 + 1200, aw7 + 1500, aw7 + 1800, cw7
    };

    float acc[NJ][4];
#pragma unroll
    for (int d = 0; d < NJ; ++d)
#pragma unroll
        for (int rr = 0; rr < 4; ++rr) acc[d][rr] = 0.0f;

#define BODY(c)                                                                     \
    {                                                                               \
        const float4 x0 = xr[0][(c)];                                               \
        const float4 x1 = xr[1][(c)];                                               \
        const float4 x2 = xr[2][(c)];                                               \
        const float4 x3 = xr[3][(c)];                                               \
        _Pragma("unroll")                                                           \
        for (int d = 0; d < NJ; ++d) {                                              \
            const float4 w = ((const float4*)wptr[d])[(c)];                         \
            acc[d][0] = fmaf(x0.w, w.w, fmaf(x0.z, w.z, fmaf(x0.y, w.y, fmaf(x0.x, w.x, acc[d][0])))); \
            acc[d][1] = fmaf(x1.w, w.w, fmaf(x1.z, w.z, fmaf(x1.y, w.y, fmaf(x1.x, w.x, acc[d][1])))); \
            acc[d][2] = fmaf(x2.w, w.w, fmaf(x2.z, w.z, fmaf(x2.y, w.y, fmaf(x2.x, w.x, acc[d][2])))); \
            acc[d][3] = fmaf(x3.w, w.w, fmaf(x3.z, w.z, fmaf(x3.y, w.y, fmaf(x3.x, w.x, acc[d][3])))); \
        }                                                                           \
    }

    BODY(j)
    BODY(j + 16)
    BODY(j + 32)
    BODY(j + 48)
    if (j < 11) {
        BODY(j + 64)
    }
#undef BODY

    // butterfly reduce each (d, rr) across the 16-lane group
#pragma unroll
    for (int d = 0; d < NJ; ++d)
#pragma unroll
        for (int rr = 0; rr < 4; ++rr) {
            float v = acc[d][rr];
            v += __shfl_xor(v, 1, 16);
            v += __shfl_xor(v, 2, 16);
            v += __shfl_xor(v, 4, 16);
            v += __shfl_xor(v, 8, 16);
            acc[d][rr] = v;
        }

    // lane j == rr stores row lr+rr into LDS (zeroed if out-of-range)
#pragma unroll
    for (int rr = 0; rr < 4; ++rr) {
        if (j == rr) {
            const float vf = valid[rr] ? 1.0f : 0.0f;
#pragma unroll
            for (int d = 0; d < NJ; ++d) dlds[lr + rr][d] = acc[d][rr] * vf;
        }
    }

    __syncthreads();

    // epilogue: thread tid < TOUT handles output l = t*TOUT + tid
    const int tid = threadIdx.x;
    if (tid < TOUT) {
        const int lo = t * TOUT + tid;
        if (lo < LL) {
            const int c = tid + 3;   // local dot-row of the center

            float pre3 = 0.0f, pre5 = 0.0f, pre7 = 0.0f;
#pragma unroll
            for (int tp = 0; tp < 3; ++tp) pre3 += dlds[c + tp - 1][tp];
#pragma unroll
            for (int tp = 0; tp < 5; ++tp) pre5 += dlds[c + tp - 2][4 + tp];
#pragma unroll
            for (int tp = 0; tp < 7; ++tp) pre7 += dlds[c + tp - 3][10 + tp];

            const float c3v = dlds[c][3];
            const float c5v = dlds[c][9];
            const float c7v = dlds[c][17];

            const float s3 = 1.0f / (1.0f + expf(-(pre3 + ab3[0])));
            const float s5 = 1.0f / (1.0f + expf(-(pre5 + ab5[0])));
            const float s7 = 1.0f / (1.0f + expf(-(pre7 + ab7[0])));

            const int r = b * LL + lo;
            out[r]             = tanhf(s3 * c3v + cb3[0]);
            out[NROWS + r]     = tanhf(s5 * c5v + cb5[0]);
            out[2 * NROWS + r] = tanhf(s7 * c7v + cb7[0]);
        }
    }
}

extern "C" void kernel_launch(void* const* d_in, const int* in_sizes, int n_in,
                              void* d_out, int out_size, void* d_ws, size_t ws_size,
                              hipStream_t stream) {
    const float* x   = (const float*)d_in[0];
    const float* aw3 = (const float*)d_in[1];
    const float* ab3 = (const float*)d_in[2];
    const float* cw3 = (const float*)d_in[3];
    const float* cb3 = (const float*)d_in[4];
    const float* aw5 = (const float*)d_in[5];
    const float* ab5 = (const float*)d_in[6];
    const float* cw5 = (const float*)d_in[7];
    const float* cb5 = (const float*)d_in[8];
    const float* aw7 = (const float*)d_in[9];
    const float* ab7 = (const float*)d_in[10];
    const float* cw7 = (const float*)d_in[11];
    const float* cb7 = (const float*)d_in[12];

    float* out = (float*)d_out;  // [out3 | out5 | out7]

    // 256 batches x 9 l-tiles, one dispatch, no workspace
    fused_kernel<<<BB * NTILE, 256, 0, stream>>>(
        x, aw3, ab3, cw3, cb3, aw5, ab5, cw5, cb5, aw7, ab7, cw7, cb7, out);
}